// Round 13
// baseline (423.983 us; speedup 1.0000x reference)
//
#include <hip/hip_runtime.h>
#include <hip/hip_bf16.h>

typedef unsigned short u16;
typedef unsigned int u32;
typedef __attribute__((ext_vector_type(8))) short short8;
typedef __attribute__((ext_vector_type(4))) float floatx4;

#define BATCH 16
#define CDIM 512
#define NSPAT 1024
#define NGROUP 8
#define NBLK 512   // persistent grid: 2 blocks/CU (32KB LDS, 256 thr, LB(256,2)) -> all co-resident

__device__ __forceinline__ u16 f2bf(float f) {
    unsigned u = __float_as_uint(f);
    u += 0x7FFFu + ((u >> 16) & 1u);   // RNE
    return (u16)(u >> 16);
}
__device__ __forceinline__ u32 f2bf2(float lo, float hi) {   // packed v_cvt_pk_bf16_f32
    __hip_bfloat162 h = __float22bfloat162_rn(make_float2(lo, hi));
    return *(u32*)&h;
}

__device__ __forceinline__ void load_lds16(const void* g, void* l) {
    __builtin_amdgcn_global_load_lds(
        (const __attribute__((address_space(1))) unsigned int*)g,
        (__attribute__((address_space(3))) unsigned int*)l, 16, 0, 0);
}

// ---- manual one-shot grid barrier (device-scope atomics + agent fences; counters pre-zeroed) ----
__device__ __forceinline__ void gridbar(u32* bar) {
    __syncthreads();
    if (threadIdx.x == 0) {
        __threadfence();                      // release: agent-scope, L2 wb across XCDs
        atomicAdd(bar, 1u);
        while (__hip_atomic_load(bar, __ATOMIC_RELAXED, __HIP_MEMORY_SCOPE_AGENT) < NBLK) {
            __builtin_amdgcn_s_sleep(2);
        }
        __threadfence();                      // acquire: invalidate stale lines
    }
    __syncthreads();
}

// ---------- shared 128x128x64 MFMA core (global_load_lds + XOR swizzle, conflict-free) ----------
__device__ __forceinline__ void gemm_core(
    const u16* Ab, const u16* Bb, int K, int lda, int ldb,
    int m0, int n0, u16* As, u16* Bs, floatx4 (&acc)[4][4]) {
    int tid = threadIdx.x;
    int lane = tid & 63, wave = tid >> 6, quad = lane >> 4, lrow = lane & 15;
    int wm = (wave >> 1) << 6, wn = (wave & 1) << 6;
    for (int k0 = 0; k0 < K; k0 += 64) {
#pragma unroll
        for (int it = 0; it < 4; ++it) {
            int c = it * 256 + tid;
            int r = c >> 3, p = c & 7;
            int kc = p ^ (r & 7);               // slot p holds global chunk p^(r&7)
            load_lds16(Ab + (size_t)(m0 + r) * lda + k0 + (kc << 3), &As[c << 3]);
            load_lds16(Bb + (size_t)(n0 + r) * ldb + k0 + (kc << 3), &Bs[c << 3]);
        }
        __syncthreads();
#pragma unroll
        for (int s = 0; s < 2; ++s) {
            short8 af[4], bf[4];
#pragma unroll
            for (int i = 0; i < 4; ++i) {
                int R = wm + i * 16 + lrow;
                int p = (s * 4 + quad) ^ (R & 7);
                af[i] = *(const short8*)&As[(R << 6) + (p << 3)];
            }
#pragma unroll
            for (int j = 0; j < 4; ++j) {
                int R = wn + j * 16 + lrow;
                int p = (s * 4 + quad) ^ (R & 7);
                bf[j] = *(const short8*)&Bs[(R << 6) + (p << 3)];
            }
#pragma unroll
            for (int i = 0; i < 4; ++i)
#pragma unroll
                for (int j = 0; j < 4; ++j)
                    acc[i][j] = __builtin_amdgcn_mfma_f32_16x16x32_bf16(af[i], bf[j], acc[i][j], 0, 0, 0);
        }
        __syncthreads();
    }
}

#define ACC_INIT floatx4 acc[4][4]; \
    _Pragma("unroll") for (int i = 0; i < 4; ++i) \
    _Pragma("unroll") for (int j = 0; j < 4; ++j) acc[i][j] = (floatx4){0.f, 0.f, 0.f, 0.f};

#define EPILOG_IDX int lane = threadIdx.x & 63, wave = threadIdx.x >> 6; \
    int quad = lane >> 4, lrow = lane & 15; \
    int wm = (wave >> 1) << 6, wn = (wave & 1) << 6;

// ================= persistent mega-kernel (regular launch + manual barriers) =================
__global__ __launch_bounds__(256, 2) void mega_kernel(
    const float* x, const float* gamma, const float* beta,
    const float* w_qkv, const float* b_qkv, const float* w_proj, const float* b_proj,
    float* out,
    float* stats, float* bpv, u16* wmega, u16* wproj_bf, u16* wv_t,
    u16* hT, u16* qkT, u16* WV, u16* P, float* lsums, u32* bars, float scale) {
    __shared__ u16 smem[2 * 128 * 64];   // 32 KB, reused across phases
    u16* As = smem;
    u16* Bs = smem + 128 * 64;
    int blk = blockIdx.x;
    int tid = threadIdx.x;

    // ---------------- P0: prep (984 work items over 512 blocks) ----------------
    for (int item = blk; item < 984; item += NBLK) {
        if (item < 768) {            // weight fp32->bf16 cvt
            const float* src = (item < 512) ? w_qkv : w_proj;
            u16* dst = (item < 512) ? wmega : wproj_bf;
            int i = (item < 512 ? item : item - 512) * 256 + tid;
            float4 v = ((const float4*)src)[i];
            u32* d = (u32*)dst;
            d[i * 2] = f2bf2(v.x, v.y);
            d[i * 2 + 1] = f2bf2(v.z, v.w);
        } else if (item < 832) {     // w_v transpose+cvt -> wv_t[ci][m]
            u16* t = smem;           // 64*66 u16
            int bt = item - 768;
            int tx = bt & 7, ty = bt >> 3;
            const float* src = w_qkv + (size_t)(1024 + ty * 64) * CDIM + tx * 64;
#pragma unroll
            for (int p = 0; p < 4; ++p) {
                int r = p * 16 + (tid >> 4);
                int c4 = (tid & 15) << 2;
                float4 v = *(const float4*)(src + (size_t)r * CDIM + c4);
                u16* d = &t[r * 66 + c4];
                d[0] = f2bf(v.x); d[1] = f2bf(v.y); d[2] = f2bf(v.z); d[3] = f2bf(v.w);
            }
            __syncthreads();
            u16* dst = wv_t + (size_t)(tx * 64) * CDIM + ty * 64;
#pragma unroll
            for (int p = 0; p < 4; ++p) {
                int c = p * 16 + (tid >> 4);
                int r4 = (tid & 15) << 2;
                ushort4 o;
                o.x = t[(r4 + 0) * 66 + c];
                o.y = t[(r4 + 1) * 66 + c];
                o.z = t[(r4 + 2) * 66 + c];
                o.w = t[(r4 + 3) * 66 + c];
                *(ushort4*)(dst + (size_t)c * CDIM + r4) = o;
            }
        } else if (item < 960) {     // GroupNorm stats
            float* rs = (float*)smem;
            int bg = item - 832;
            const float4* xv = (const float4*)(x + (size_t)bg * 65536);
            float s = 0.f, ss = 0.f;
            for (int i = tid; i < 16384; i += 256) {
                float4 v = xv[i];
                s += v.x + v.y + v.z + v.w;
                ss += v.x * v.x + v.y * v.y + v.z * v.z + v.w * v.w;
            }
#pragma unroll
            for (int off = 32; off; off >>= 1) { s += __shfl_down(s, off); ss += __shfl_down(ss, off); }
            int wv = tid >> 6, lane = tid & 63;
            if (lane == 0) { rs[wv] = s; rs[4 + wv] = ss; }
            __syncthreads();
            if (tid == 0) {
                float S1 = rs[0] + rs[1] + rs[2] + rs[3];
                float S2 = rs[4] + rs[5] + rs[6] + rs[7];
                float mean = S1 * (1.f / 65536.f);
                float var = S2 * (1.f / 65536.f) - mean * mean;
                stats[bg * 2] = mean;
                stats[bg * 2 + 1] = rsqrtf(var + 1e-5f);
            }
        } else if (item < 976) {     // zero lsums
            ((float4*)lsums)[(item - 960) * 256 + tid] = (float4){0.f, 0.f, 0.f, 0.f};
        } else {                     // bpv[o] = sum_c w_proj[o][c]*b_qkv[1024+c]
            int o0 = (item - 976) * 64;
            int wv = tid >> 6, lane = tid & 63;
            const float4* bvv = (const float4*)(b_qkv + 1024);
            float4 v0 = bvv[lane * 2], v1 = bvv[lane * 2 + 1];
            for (int it = 0; it < 16; ++it) {
                int o = o0 + wv * 16 + it;
                const float4* wr = (const float4*)(w_proj + (size_t)o * CDIM);
                float4 a0 = wr[lane * 2], a1 = wr[lane * 2 + 1];
                float s = a0.x * v0.x + a0.y * v0.y + a0.z * v0.z + a0.w * v0.w
                        + a1.x * v1.x + a1.y * v1.y + a1.z * v1.z + a1.w * v1.w;
#pragma unroll
                for (int off = 32; off; off >>= 1) s += __shfl_down(s, off);
                if (lane == 0) bpv[o] = s;
            }
        }
        __syncthreads();
    }
    gridbar(&bars[0]);

    // ---------------- P0.5: GN apply+transpose (2048 tiles, 4/block) + Wpv (16 blocks) ----------------
    for (int t = blk * 4; t < blk * 4 + 4; ++t) {
        u16* tb = smem;
        int z = t & 15, rem = t >> 4;
        int c0 = (rem & 7) << 6, n0 = (rem >> 3) << 6;
        const float* xb = x + ((size_t)z * CDIM + c0) * NSPAT + n0;
#pragma unroll
        for (int p = 0; p < 4; ++p) {
            int cl = p * 16 + (tid >> 4);
            int nl = (tid & 15) << 2;
            int c = c0 + cl;
            int bg = z * NGROUP + (c >> 6);
            float ga = gamma[c] * stats[bg * 2 + 1];
            float be = beta[c] - stats[bg * 2] * ga;
            float4 v = *(const float4*)(xb + (size_t)cl * NSPAT + nl);
            u16* dst = &tb[cl * 66 + nl];
            dst[0] = f2bf(v.x * ga + be);
            dst[1] = f2bf(v.y * ga + be);
            dst[2] = f2bf(v.z * ga + be);
            dst[3] = f2bf(v.w * ga + be);
        }
        __syncthreads();
        u16* hb = hT + ((size_t)z * NSPAT + n0) * CDIM + c0;
#pragma unroll
        for (int p = 0; p < 4; ++p) {
            int nl = p * 16 + (tid >> 4);
            int cl4 = (tid & 15) << 2;
            ushort4 o;
            o.x = tb[(cl4 + 0) * 66 + nl];
            o.y = tb[(cl4 + 1) * 66 + nl];
            o.z = tb[(cl4 + 2) * 66 + nl];
            o.w = tb[(cl4 + 3) * 66 + nl];
            *(ushort4*)(hb + (size_t)nl * CDIM + cl4) = o;
        }
        __syncthreads();
    }
    if (blk < 16) {   // Wpv = wproj_bf . wv_t^T -> wmega rows 1024..1535
        int m0 = (blk >> 2) << 7, n0 = (blk & 3) << 7;
        ACC_INIT;
        gemm_core(wproj_bf, wv_t, CDIM, CDIM, CDIM, m0, n0, As, Bs, acc);
        EPILOG_IDX;
#pragma unroll
        for (int i = 0; i < 4; ++i)
#pragma unroll
            for (int j = 0; j < 4; ++j)
#pragma unroll
                for (int r = 0; r < 4; ++r) {
                    int R = m0 + wm + i * 16 + (quad << 2) + r;
                    int Cc = n0 + wn + j * 16 + lrow;
                    wmega[(size_t)(1024 + R) * CDIM + Cc] = f2bf(acc[i][j][r]);
                }
    }
    gridbar(&bars[1]);

    // ---------------- P1: qkv-mega [q;k;WV] (1536 tiles, 3/block) ----------------
    for (int t = blk; t < 1536; t += NBLK) {
        int z = t & 15, rem = t >> 4;            // rem 0..95
        int m0 = (rem % 12) << 7, n0 = (rem / 12) << 7;
        const u16* Bb = hT + (size_t)z * CDIM * NSPAT;
        ACC_INIT;
        gemm_core(wmega, Bb, CDIM, CDIM, CDIM, m0, n0, As, Bs, acc);
        EPILOG_IDX;
        if (m0 < 1024) {   // q,k rows: transposed packed store qkT[n][o]
            u16* qk = qkT + (size_t)z * NSPAT * NSPAT;
#pragma unroll
            for (int i = 0; i < 4; ++i)
#pragma unroll
                for (int j = 0; j < 4; ++j) {
                    int R0 = m0 + wm + i * 16 + (quad << 2);
                    int Cc = n0 + wn + j * 16 + lrow;
                    uint2 u;
                    u.x = f2bf2(acc[i][j][0] + b_qkv[R0 + 0], acc[i][j][1] + b_qkv[R0 + 1]);
                    u.y = f2bf2(acc[i][j][2] + b_qkv[R0 + 2], acc[i][j][3] + b_qkv[R0 + 3]);
                    *(uint2*)&qk[(size_t)Cc * NSPAT + R0] = u;
                }
        } else {           // WV rows: natural store + bpv
            u16* Wp = WV + (size_t)z * CDIM * NSPAT;
#pragma unroll
            for (int i = 0; i < 4; ++i)
#pragma unroll
                for (int j = 0; j < 4; ++j)
#pragma unroll
                    for (int r = 0; r < 4; ++r) {
                        int R = m0 - 1024 + wm + i * 16 + (quad << 2) + r;
                        int Cc = n0 + wn + j * 16 + lrow;
                        Wp[(size_t)R * NSPAT + Cc] = f2bf(acc[i][j][r] + bpv[R]);
                    }
        }
    }
    gridbar(&bars[2]);

    // ---------------- P2: scores P = exp(scale*q^T k), fused row sums (1024 tiles, 2/block) ----------------
    for (int t = blk; t < 1024; t += NBLK) {
        int z = t & 15, rem = t >> 4;            // rem 0..63
        int m0 = (rem & 7) << 7, n0 = (rem >> 3) << 7;
        const u16* qb = qkT + (size_t)z * NSPAT * NSPAT;
        ACC_INIT;
        gemm_core(qb, qb + CDIM, CDIM, NSPAT, NSPAT, m0, n0, As, Bs, acc);
        EPILOG_IDX;
        u16* Pp = P + (size_t)z * NSPAT * NSPAT;
        float rowpart[4][4];
#pragma unroll
        for (int i = 0; i < 4; ++i)
#pragma unroll
            for (int r = 0; r < 4; ++r) rowpart[i][r] = 0.f;
#pragma unroll
        for (int i = 0; i < 4; ++i)
#pragma unroll
            for (int j = 0; j < 4; ++j)
#pragma unroll
                for (int r = 0; r < 4; ++r) {
                    int R = m0 + wm + i * 16 + (quad << 2) + r;
                    int Cc = n0 + wn + j * 16 + lrow;
                    float e = __expf(acc[i][j][r] * scale);
                    rowpart[i][r] += e;
                    Pp[(size_t)R * NSPAT + Cc] = f2bf(e);
                }
#pragma unroll
        for (int i = 0; i < 4; ++i)
#pragma unroll
            for (int r = 0; r < 4; ++r) {
                float v = rowpart[i][r];
#pragma unroll
                for (int m = 1; m < 16; m <<= 1) v += __shfl_xor(v, m);
                if (lrow == 0) {
                    int R = m0 + wm + i * 16 + (quad << 2) + r;
                    atomicAdd(&lsums[(size_t)z * NSPAT + R], v);
                }
            }
    }
    gridbar(&bars[3]);

    // ---------------- P3: final out = WV.P^T / l + b_proj + x (512 tiles, 1/block) ----------------
    {
        int t = blk;
        int z = t & 15, rem = t >> 4;             // rem 0..31
        int m0 = (rem & 3) << 7, n0 = (rem >> 2) << 7;
        const u16* Ab = WV + (size_t)z * CDIM * NSPAT;
        const u16* Bb = P + (size_t)z * NSPAT * NSPAT;
        ACC_INIT;
        gemm_core(Ab, Bb, NSPAT, NSPAT, NSPAT, m0, n0, As, Bs, acc);
        EPILOG_IDX;
        float* Op = out + (size_t)z * CDIM * NSPAT;
        const float* xr = x + (size_t)z * CDIM * NSPAT;
        const float* li = lsums + (size_t)z * NSPAT;
#pragma unroll
        for (int i = 0; i < 4; ++i)
#pragma unroll
            for (int j = 0; j < 4; ++j) {
                int Cc = n0 + wn + j * 16 + lrow;
                float sc = __builtin_amdgcn_rcpf(li[Cc]);
#pragma unroll
                for (int r = 0; r < 4; ++r) {
                    int R = m0 + wm + i * 16 + (quad << 2) + r;
                    size_t off = (size_t)R * NSPAT + Cc;
                    Op[off] = acc[i][j][r] * sc + b_proj[R] + xr[off];
                }
            }
    }
}

// ================= launch =================
extern "C" void kernel_launch(void* const* d_in, const int* in_sizes, int n_in,
                              void* d_out, int out_size, void* d_ws, size_t ws_size,
                              hipStream_t stream) {
    const float* x      = (const float*)d_in[0];
    const float* gamma  = (const float*)d_in[1];
    const float* beta   = (const float*)d_in[2];
    const float* w_qkv  = (const float*)d_in[3];
    const float* b_qkv  = (const float*)d_in[4];
    const float* w_proj = (const float*)d_in[5];
    const float* b_proj = (const float*)d_in[6];
    float* out = (float*)d_out;

    const size_t CN = (size_t)CDIM * NSPAT;
    const size_t NN = (size_t)NSPAT * NSPAT;
    float scale = 0.044194173824159216f;

    char* ws = (char*)d_ws;
    float* stats   = (float*)ws;                              // 1 KB
    float* bpv     = (float*)(ws + 1024);                     // 2 KB
    u16* wmega     = (u16*)(ws + 4096);                       // [Wq;Wk;Wpv] 1536x512 bf16
    u16* wproj_bf  = wmega + (size_t)3 * CDIM * CDIM;
    u16* wv_t      = wproj_bf + (size_t)CDIM * CDIM;
    u16* hT        = wv_t + (size_t)CDIM * CDIM;              // 16.8 MB
    u16* qkT       = hT + BATCH * CN;                         // 33.5 MB
    u16* WV        = qkT + BATCH * NN;                        // 16.8 MB
    u16* P         = WV + BATCH * CN;                         // 33.5 MB
    float* lsums   = (float*)(P + BATCH * NN);                // 64 KB
    u32* bars      = (u32*)(lsums + BATCH * NSPAT);           // 16 B barrier counters

    (void)hipMemsetAsync(bars, 0, 4 * sizeof(u32), stream);

    mega_kernel<<<NBLK, 256, 0, stream>>>(
        x, gamma, beta, w_qkv, b_qkv, w_proj, b_proj, out,
        stats, bpv, wmega, wproj_bf, wv_t, hT, qkT, WV, P, lsums, bars, scale);
}

// Round 14
// 239.652 us; speedup vs baseline: 1.7692x; 1.7692x over previous
//
#include <hip/hip_runtime.h>
#include <hip/hip_bf16.h>

typedef unsigned short u16;
typedef unsigned int u32;
typedef __attribute__((ext_vector_type(8))) short short8;
typedef __attribute__((ext_vector_type(4))) float floatx4;

#define BATCH 16
#define CDIM 512
#define NSPAT 1024
#define NGROUP 8

__device__ __forceinline__ u16 f2bf(float f) {
    unsigned u = __float_as_uint(f);
    u += 0x7FFFu + ((u >> 16) & 1u);   // RNE
    return (u16)(u >> 16);
}
__device__ __forceinline__ u32 f2bf2(float lo, float hi) {   // packed v_cvt_pk_bf16_f32
    __hip_bfloat162 h = __float22bfloat162_rn(make_float2(lo, hi));
    return *(u32*)&h;
}

__device__ __forceinline__ void load_lds16(const void* g, void* l) {
    __builtin_amdgcn_global_load_lds(
        (const __attribute__((address_space(1))) unsigned int*)g,
        (__attribute__((address_space(3))) unsigned int*)l, 16, 0, 0);
}

// ================= D1 prep =================
// blocks [0,512): w_qkv rows 0..1023 cvt -> wmega rows 0..1023
//        [512,768): w_proj cvt -> wproj_bf
//        [768,832): w_v transpose+cvt -> wv_t[ci][m]
//        [832,960): GroupNorm stats
//        [960,976): lsums zero
//        [976,984): bpv[o] = sum_c w_proj[o][c] * b_qkv[1024+c]
__global__ __launch_bounds__(256) void prep_kernel(
    const float* __restrict__ w_qkv, const float* __restrict__ w_proj,
    const float* __restrict__ b_qkv, const float* __restrict__ x,
    u16* __restrict__ wmega, u16* __restrict__ wproj_bf, u16* __restrict__ wv_t,
    float* __restrict__ stats, float* __restrict__ lsums, float* __restrict__ bpv) {
    int b = blockIdx.x;
    int tid = threadIdx.x;
    if (b < 768) {
        const float* src = (b < 512) ? w_qkv : w_proj;
        u16* dst = (b < 512) ? wmega : wproj_bf;
        int i = (b < 512 ? b : b - 512) * 256 + tid;
        float4 v = ((const float4*)src)[i];
        u32* d = (u32*)dst;
        d[i * 2] = f2bf2(v.x, v.y);
        d[i * 2 + 1] = f2bf2(v.z, v.w);
        return;
    }
    if (b < 832) {  // transpose w_v (rows 1024..1535 of w_qkv) -> wv_t[ci][m], 64x64 tiles
        __shared__ u16 t[64 * 66];
        int bt = b - 768;
        int tx = bt & 7, ty = bt >> 3;
        const float* src = w_qkv + (size_t)(1024 + ty * 64) * CDIM + tx * 64;
#pragma unroll
        for (int p = 0; p < 4; ++p) {
            int r = p * 16 + (tid >> 4);
            int c4 = (tid & 15) << 2;
            float4 v = *(const float4*)(src + (size_t)r * CDIM + c4);
            u16* d = &t[r * 66 + c4];
            d[0] = f2bf(v.x); d[1] = f2bf(v.y); d[2] = f2bf(v.z); d[3] = f2bf(v.w);
        }
        __syncthreads();
        u16* dst = wv_t + (size_t)(tx * 64) * CDIM + ty * 64;
#pragma unroll
        for (int p = 0; p < 4; ++p) {
            int c = p * 16 + (tid >> 4);
            int r4 = (tid & 15) << 2;
            ushort4 o;
            o.x = t[(r4 + 0) * 66 + c];
            o.y = t[(r4 + 1) * 66 + c];
            o.z = t[(r4 + 2) * 66 + c];
            o.w = t[(r4 + 3) * 66 + c];
            *(ushort4*)(dst + (size_t)c * CDIM + r4) = o;
        }
        return;
    }
    if (b < 960) {  // stats
        __shared__ float rs[4], rss[4];
        int bg = b - 832;
        const float4* xv = (const float4*)(x + (size_t)bg * 65536);
        float s = 0.f, ss = 0.f;
        for (int i = tid; i < 16384; i += 256) {
            float4 v = xv[i];
            s += v.x + v.y + v.z + v.w;
            ss += v.x * v.x + v.y * v.y + v.z * v.z + v.w * v.w;
        }
#pragma unroll
        for (int off = 32; off; off >>= 1) { s += __shfl_down(s, off); ss += __shfl_down(ss, off); }
        int wave = tid >> 6, lane = tid & 63;
        if (lane == 0) { rs[wave] = s; rss[wave] = ss; }
        __syncthreads();
        if (tid == 0) {
            float S1 = rs[0] + rs[1] + rs[2] + rs[3];
            float S2 = rss[0] + rss[1] + rss[2] + rss[3];
            float mean = S1 * (1.f / 65536.f);
            float var = S2 * (1.f / 65536.f) - mean * mean;
            stats[bg * 2] = mean;
            stats[bg * 2 + 1] = rsqrtf(var + 1e-5f);
        }
        return;
    }
    if (b < 976) {  // zero lsums
        ((float4*)lsums)[(b - 960) * 256 + tid] = (float4){0.f, 0.f, 0.f, 0.f};
        return;
    }
    {   // bpv
        int o0 = (b - 976) * 64;
        int wave = tid >> 6, lane = tid & 63;
        const float4* bvv = (const float4*)(b_qkv + 1024);
        float4 v0 = bvv[lane * 2], v1 = bvv[lane * 2 + 1];
        for (int it = 0; it < 16; ++it) {
            int o = o0 + wave * 16 + it;
            const float4* wr = (const float4*)(w_proj + (size_t)o * CDIM);
            float4 a0 = wr[lane * 2], a1 = wr[lane * 2 + 1];
            float s = a0.x * v0.x + a0.y * v0.y + a0.z * v0.z + a0.w * v0.w
                    + a1.x * v1.x + a1.y * v1.y + a1.z * v1.z + a1.w * v1.w;
#pragma unroll
            for (int off = 32; off; off >>= 1) s += __shfl_down(s, off);
            if (lane == 0) bpv[o] = s;
        }
    }
}

// ================= shared 128x128x64 MFMA core (global_load_lds + XOR swizzle) =================
__device__ __forceinline__ void gemm_core(
    const u16* __restrict__ Ab, const u16* __restrict__ Bb, int K, int lda, int ldb,
    int m0, int n0, u16* As, u16* Bs, floatx4 (&acc)[4][4]) {
    int tid = threadIdx.x;
    int lane = tid & 63, wave = tid >> 6, quad = lane >> 4, lrow = lane & 15;
    int wm = (wave >> 1) << 6, wn = (wave & 1) << 6;
    for (int k0 = 0; k0 < K; k0 += 64) {
#pragma unroll
        for (int it = 0; it < 4; ++it) {
            int c = it * 256 + tid;
            int r = c >> 3, p = c & 7;
            int kc = p ^ (r & 7);               // slot p holds global chunk p^(r&7)
            load_lds16(Ab + (size_t)(m0 + r) * lda + k0 + (kc << 3), &As[c << 3]);
            load_lds16(Bb + (size_t)(n0 + r) * ldb + k0 + (kc << 3), &Bs[c << 3]);
        }
        __syncthreads();
#pragma unroll
        for (int s = 0; s < 2; ++s) {
            short8 af[4], bf[4];
#pragma unroll
            for (int i = 0; i < 4; ++i) {
                int R = wm + i * 16 + lrow;
                int p = (s * 4 + quad) ^ (R & 7);
                af[i] = *(const short8*)&As[(R << 6) + (p << 3)];
            }
#pragma unroll
            for (int j = 0; j < 4; ++j) {
                int R = wn + j * 16 + lrow;
                int p = (s * 4 + quad) ^ (R & 7);
                bf[j] = *(const short8*)&Bs[(R << 6) + (p << 3)];
            }
#pragma unroll
            for (int i = 0; i < 4; ++i)
#pragma unroll
                for (int j = 0; j < 4; ++j)
                    acc[i][j] = __builtin_amdgcn_mfma_f32_16x16x32_bf16(af[i], bf[j], acc[i][j], 0, 0, 0);
        }
        __syncthreads();
    }
}

#define ACC_INIT floatx4 acc[4][4]; \
    _Pragma("unroll") for (int i = 0; i < 4; ++i) \
    _Pragma("unroll") for (int j = 0; j < 4; ++j) acc[i][j] = (floatx4){0.f, 0.f, 0.f, 0.f};

#define EPILOG_IDX int lane = threadIdx.x & 63, wave = threadIdx.x >> 6; \
    int quad = lane >> 4, lrow = lane & 15; \
    int wm = (wave >> 1) << 6, wn = (wave & 1) << 6;

// ================= D2: GN apply+transpose (z<16) + Wpv GEMM (z==16) =================
#define TSTR 66
__global__ __launch_bounds__(256) void gn_wpv_kernel(
    const float* __restrict__ x, const float* __restrict__ gamma, const float* __restrict__ beta,
    const float* __restrict__ stats, u16* __restrict__ hT,
    const u16* __restrict__ wproj_bf, const u16* __restrict__ wv_t, u16* __restrict__ wmega) {
    __shared__ u16 smem[2 * 128 * 64];
    int tid = threadIdx.x;
    if (blockIdx.z == 16) {  // Wpv = wproj_bf . wv_t^T -> wmega rows 1024..1535
        if (blockIdx.x >= 4 || blockIdx.y >= 4) return;
        int m0 = blockIdx.y << 7, n0 = blockIdx.x << 7;
        ACC_INIT;
        gemm_core(wproj_bf, wv_t, CDIM, CDIM, CDIM, m0, n0, smem, smem + 128 * 64, acc);
        EPILOG_IDX;
#pragma unroll
        for (int i = 0; i < 4; ++i)
#pragma unroll
            for (int j = 0; j < 4; ++j)
#pragma unroll
                for (int r = 0; r < 4; ++r) {
                    int R = m0 + wm + i * 16 + (quad << 2) + r;
                    int Cc = n0 + wn + j * 16 + lrow;
                    wmega[(size_t)(1024 + R) * CDIM + Cc] = f2bf(acc[i][j][r]);
                }
        return;
    }
    u16* t = smem;
    int b = blockIdx.z, c0 = blockIdx.y << 6, n0 = blockIdx.x << 6;
    const float* xb = x + ((size_t)b * CDIM + c0) * NSPAT + n0;
#pragma unroll
    for (int p = 0; p < 4; ++p) {
        int cl = p * 16 + (tid >> 4);
        int nl = (tid & 15) << 2;
        int c = c0 + cl;
        int bg = b * NGROUP + (c >> 6);
        float ga = gamma[c] * stats[bg * 2 + 1];
        float be = beta[c] - stats[bg * 2] * ga;
        float4 v = *(const float4*)(xb + (size_t)cl * NSPAT + nl);
        u16* dst = &t[cl * TSTR + nl];
        dst[0] = f2bf(v.x * ga + be);
        dst[1] = f2bf(v.y * ga + be);
        dst[2] = f2bf(v.z * ga + be);
        dst[3] = f2bf(v.w * ga + be);
    }
    __syncthreads();
    u16* hb = hT + ((size_t)b * NSPAT + n0) * CDIM + c0;
#pragma unroll
    for (int p = 0; p < 4; ++p) {
        int nl = p * 16 + (tid >> 4);
        int cl4 = (tid & 15) << 2;
        ushort4 o;
        o.x = t[(cl4 + 0) * TSTR + nl];
        o.y = t[(cl4 + 1) * TSTR + nl];
        o.z = t[(cl4 + 2) * TSTR + nl];
        o.w = t[(cl4 + 3) * TSTR + nl];
        *(ushort4*)(hb + (size_t)nl * CDIM + cl4) = o;
    }
}

// ================= D3: qkv-mega: [q;k;WV] = wmega . h + [b_qkv(qk); bpv] =================
// grid (BATCH, 8, 12): batch in x for XCD affinity.
__global__ __launch_bounds__(256) void qkv_kernel(
    const u16* __restrict__ wmega, const u16* __restrict__ hT,
    const float* __restrict__ b_qkv, const float* __restrict__ bpv,
    u16* __restrict__ qkT, u16* __restrict__ WV) {
    __shared__ u16 As[128 * 64];
    __shared__ u16 Bs[128 * 64];
    int z = blockIdx.x;
    int n0 = blockIdx.y << 7;
    int m0 = blockIdx.z << 7;
    const u16* Bb = hT + (size_t)z * CDIM * NSPAT;
    ACC_INIT;
    gemm_core(wmega, Bb, CDIM, CDIM, CDIM, m0, n0, As, Bs, acc);
    EPILOG_IDX;
    if (blockIdx.z < 8) {  // q,k rows: transposed packed store to qkT[n][o], ldc=1024
        u16* qk = qkT + (size_t)z * NSPAT * NSPAT;
#pragma unroll
        for (int i = 0; i < 4; ++i)
#pragma unroll
            for (int j = 0; j < 4; ++j) {
                int R0 = m0 + wm + i * 16 + (quad << 2);
                int Cc = n0 + wn + j * 16 + lrow;
                uint2 u;
                u.x = f2bf2(acc[i][j][0] + b_qkv[R0 + 0], acc[i][j][1] + b_qkv[R0 + 1]);
                u.y = f2bf2(acc[i][j][2] + b_qkv[R0 + 2], acc[i][j][3] + b_qkv[R0 + 3]);
                *(uint2*)&qk[(size_t)Cc * NSPAT + R0] = u;
            }
    } else {  // WV rows: natural store WV[o][n] + bpv
        u16* Wp = WV + (size_t)z * CDIM * NSPAT;
#pragma unroll
        for (int i = 0; i < 4; ++i)
#pragma unroll
            for (int j = 0; j < 4; ++j)
#pragma unroll
                for (int r = 0; r < 4; ++r) {
                    int R = m0 - 1024 + wm + i * 16 + (quad << 2) + r;
                    int Cc = n0 + wn + j * 16 + lrow;
                    Wp[(size_t)R * NSPAT + Cc] = f2bf(acc[i][j][r] + bpv[R]);
                }
    }
}

// ================= D4: scores (swapped operands): D[j][i] = k_j . q_i =================
// A = kT rows (M=j), B = qT rows (N=i)  ->  C/D col=i (lane), row=j (reg).
// P[i][j] store becomes contiguous uint2; row-sum reduce = 2 shuffle steps across quads.
// grid (BATCH, 8, 8): y = i-tile, z = j-tile.
__global__ __launch_bounds__(256) void scores_kernel(
    const u16* __restrict__ qkT, u16* __restrict__ P, float* __restrict__ lsums, float scale) {
    __shared__ u16 As[128 * 64];
    __shared__ u16 Bs[128 * 64];
    int z = blockIdx.x;
    int n0 = blockIdx.y << 7;                // i tile (N-dim)
    int m0 = blockIdx.z << 7;                // j tile (M-dim)
    const u16* qb = qkT + (size_t)z * NSPAT * NSPAT;
    ACC_INIT;
    gemm_core(qb + CDIM, qb, CDIM, NSPAT, NSPAT, m0, n0, As, Bs, acc);
    EPILOG_IDX;
    u16* Pp = P + (size_t)z * NSPAT * NSPAT;
    float* ls = lsums + (size_t)z * NSPAT;
#pragma unroll
    for (int nj = 0; nj < 4; ++nj) {
        int Ci = n0 + wn + nj * 16 + lrow;       // i (column of D)
        float part = 0.f;
#pragma unroll
        for (int mi = 0; mi < 4; ++mi) {
            int Rj0 = m0 + wm + mi * 16 + (quad << 2);   // j (rows of D), 4 consecutive
            float e0 = __expf(acc[mi][nj][0] * scale);
            float e1 = __expf(acc[mi][nj][1] * scale);
            float e2 = __expf(acc[mi][nj][2] * scale);
            float e3 = __expf(acc[mi][nj][3] * scale);
            part += (e0 + e1) + (e2 + e3);
            uint2 u;
            u.x = f2bf2(e0, e1);
            u.y = f2bf2(e2, e3);
            *(uint2*)&Pp[(size_t)Ci * NSPAT + Rj0] = u;
        }
        // reduce the per-lane partial (64 j's per wave) across the 4 quads (same Ci)
        part += __shfl_xor(part, 16);
        part += __shfl_xor(part, 32);
        if (lane < 16) atomicAdd(&ls[Ci], part);
    }
}

// ================= D5: final (swapped operands): D[i][o] = P_i . WV_o =================
// A = P rows (M=i), B = WV rows (N=o)  ->  col=o (lane), row=i (reg, 4 consecutive).
// out[o][i] / x[o][i] / lsums[i] all become float4 accesses.
// grid (BATCH, 4, 8): y = o-tile, z = i-tile.
__global__ __launch_bounds__(256) void final_kernel(
    const u16* __restrict__ WV, const u16* __restrict__ P, const float* __restrict__ lsums,
    const float* __restrict__ bias, const float* __restrict__ x, float* __restrict__ out) {
    __shared__ u16 As[128 * 64];
    __shared__ u16 Bs[128 * 64];
    int z = blockIdx.x;
    int n0 = blockIdx.y << 7;                // o tile (N-dim, 4 tiles)
    int m0 = blockIdx.z << 7;                // i tile (M-dim, 8 tiles)
    const u16* Pb = P + (size_t)z * NSPAT * NSPAT;
    const u16* WVb = WV + (size_t)z * CDIM * NSPAT;
    ACC_INIT;
    gemm_core(Pb, WVb, NSPAT, NSPAT, NSPAT, m0, n0, As, Bs, acc);
    EPILOG_IDX;
    float* Op = out + (size_t)z * CDIM * NSPAT;
    const float* xr = x + (size_t)z * CDIM * NSPAT;
    const float* li = lsums + (size_t)z * NSPAT;
#pragma unroll
    for (int mi = 0; mi < 4; ++mi) {
        int Ri0 = m0 + wm + mi * 16 + (quad << 2);       // i, 4 consecutive
        float4 lv = *(const float4*)&li[Ri0];
        float s0 = __builtin_amdgcn_rcpf(lv.x);
        float s1 = __builtin_amdgcn_rcpf(lv.y);
        float s2 = __builtin_amdgcn_rcpf(lv.z);
        float s3 = __builtin_amdgcn_rcpf(lv.w);
#pragma unroll
        for (int nj = 0; nj < 4; ++nj) {
            int Co = n0 + wn + nj * 16 + lrow;           // o
            float bv = bias[Co];
            size_t off = (size_t)Co * NSPAT + Ri0;
            float4 xv = *(const float4*)&xr[off];
            float4 o;
            o.x = acc[mi][nj][0] * s0 + bv + xv.x;
            o.y = acc[mi][nj][1] * s1 + bv + xv.y;
            o.z = acc[mi][nj][2] * s2 + bv + xv.z;
            o.w = acc[mi][nj][3] * s3 + bv + xv.w;
            *(float4*)&Op[off] = o;
        }
    }
}

// ================= launch =================
extern "C" void kernel_launch(void* const* d_in, const int* in_sizes, int n_in,
                              void* d_out, int out_size, void* d_ws, size_t ws_size,
                              hipStream_t stream) {
    const float* x      = (const float*)d_in[0];
    const float* gamma  = (const float*)d_in[1];
    const float* beta   = (const float*)d_in[2];
    const float* w_qkv  = (const float*)d_in[3];
    const float* b_qkv  = (const float*)d_in[4];
    const float* w_proj = (const float*)d_in[5];
    const float* b_proj = (const float*)d_in[6];
    float* out = (float*)d_out;

    const size_t CN = (size_t)CDIM * NSPAT;   // 524288
    const size_t NN = (size_t)NSPAT * NSPAT;  // 1048576
    const float SCALE = 0.044194173824159216f;

    char* ws = (char*)d_ws;
    float* stats   = (float*)ws;                              // 1 KB
    float* bpv     = (float*)(ws + 1024);                     // 2 KB
    u16* wmega     = (u16*)(ws + 4096);                       // [Wq;Wk;Wpv] 1536x512 bf16
    u16* wproj_bf  = wmega + (size_t)3 * CDIM * CDIM;         // 0.5 MB
    u16* wv_t      = wproj_bf + (size_t)CDIM * CDIM;          // 0.5 MB
    u16* hT        = wv_t + (size_t)CDIM * CDIM;              // 16.8 MB [n][c]
    u16* qkT       = hT + BATCH * CN;                         // 33.5 MB [n][q,k:1024]
    u16* WV        = qkT + BATCH * NN;                        // 16.8 MB [o][n]
    u16* P         = WV + BATCH * CN;                         // 33.5 MB [i][j] unnorm
    float* lsums   = (float*)(P + BATCH * NN);                // 64 KB

    prep_kernel<<<984, 256, 0, stream>>>(
        w_qkv, w_proj, b_qkv, x, wmega, wproj_bf, wv_t, stats, lsums, bpv);

    gn_wpv_kernel<<<dim3(16, 8, 17), 256, 0, stream>>>(
        x, gamma, beta, stats, hT, wproj_bf, wv_t, wmega);

    qkv_kernel<<<dim3(BATCH, 8, 12), 256, 0, stream>>>(
        wmega, hT, b_qkv, bpv, qkT, WV);

    scores_kernel<<<dim3(BATCH, 8, 8), 256, 0, stream>>>(qkT, P, lsums, SCALE);

    final_kernel<<<dim3(BATCH, 4, 8), 256, 0, stream>>>(WV, P, lsums, b_proj, x, out);
}

// Round 16
// 239.409 us; speedup vs baseline: 1.7710x; 1.0010x over previous
//
#include <hip/hip_runtime.h>
#include <hip/hip_bf16.h>

typedef unsigned short u16;
typedef unsigned int u32;
typedef __attribute__((ext_vector_type(8))) short short8;
typedef __attribute__((ext_vector_type(4))) float floatx4;

#define BATCH 16
#define CDIM 512
#define NSPAT 1024
#define NGROUP 8

__device__ __forceinline__ u16 f2bf(float f) {
    unsigned u = __float_as_uint(f);
    u += 0x7FFFu + ((u >> 16) & 1u);   // RNE
    return (u16)(u >> 16);
}
__device__ __forceinline__ u32 f2bf2(float lo, float hi) {   // packed v_cvt_pk_bf16_f32
    __hip_bfloat162 h = __float22bfloat162_rn(make_float2(lo, hi));
    return *(u32*)&h;
}

__device__ __forceinline__ void load_lds16(const void* g, void* l) {
    __builtin_amdgcn_global_load_lds(
        (const __attribute__((address_space(1))) unsigned int*)g,
        (__attribute__((address_space(3))) unsigned int*)l, 16, 0, 0);
}

// ================= D1 prep =================
// blocks [0,512): w_qkv rows 0..1023 cvt -> wmega rows 0..1023
//        [512,768): w_proj cvt -> wproj_bf
//        [768,832): w_v transpose+cvt -> wv_t[ci][m]
//        [832,960): GroupNorm stats
//        [960,976): lsums zero
//        [976,984): bpv[o] = sum_c w_proj[o][c] * b_qkv[1024+c]
__global__ __launch_bounds__(256) void prep_kernel(
    const float* __restrict__ w_qkv, const float* __restrict__ w_proj,
    const float* __restrict__ b_qkv, const float* __restrict__ x,
    u16* __restrict__ wmega, u16* __restrict__ wproj_bf, u16* __restrict__ wv_t,
    float* __restrict__ stats, float* __restrict__ lsums, float* __restrict__ bpv) {
    int b = blockIdx.x;
    int tid = threadIdx.x;
    if (b < 768) {
        const float* src = (b < 512) ? w_qkv : w_proj;
        u16* dst = (b < 512) ? wmega : wproj_bf;
        int i = (b < 512 ? b : b - 512) * 256 + tid;
        float4 v = ((const float4*)src)[i];
        u32* d = (u32*)dst;
        d[i * 2] = f2bf2(v.x, v.y);
        d[i * 2 + 1] = f2bf2(v.z, v.w);
        return;
    }
    if (b < 832) {  // transpose w_v (rows 1024..1535 of w_qkv) -> wv_t[ci][m], 64x64 tiles
        __shared__ u16 t[64 * 66];
        int bt = b - 768;
        int tx = bt & 7, ty = bt >> 3;
        const float* src = w_qkv + (size_t)(1024 + ty * 64) * CDIM + tx * 64;
#pragma unroll
        for (int p = 0; p < 4; ++p) {
            int r = p * 16 + (tid >> 4);
            int c4 = (tid & 15) << 2;
            float4 v = *(const float4*)(src + (size_t)r * CDIM + c4);
            u16* d = &t[r * 66 + c4];
            d[0] = f2bf(v.x); d[1] = f2bf(v.y); d[2] = f2bf(v.z); d[3] = f2bf(v.w);
        }
        __syncthreads();
        u16* dst = wv_t + (size_t)(tx * 64) * CDIM + ty * 64;
#pragma unroll
        for (int p = 0; p < 4; ++p) {
            int c = p * 16 + (tid >> 4);
            int r4 = (tid & 15) << 2;
            ushort4 o;
            o.x = t[(r4 + 0) * 66 + c];
            o.y = t[(r4 + 1) * 66 + c];
            o.z = t[(r4 + 2) * 66 + c];
            o.w = t[(r4 + 3) * 66 + c];
            *(ushort4*)(dst + (size_t)c * CDIM + r4) = o;
        }
        return;
    }
    if (b < 960) {  // stats
        __shared__ float rs[4], rss[4];
        int bg = b - 832;
        const float4* xv = (const float4*)(x + (size_t)bg * 65536);
        float s = 0.f, ss = 0.f;
        for (int i = tid; i < 16384; i += 256) {
            float4 v = xv[i];
            s += v.x + v.y + v.z + v.w;
            ss += v.x * v.x + v.y * v.y + v.z * v.z + v.w * v.w;
        }
#pragma unroll
        for (int off = 32; off; off >>= 1) { s += __shfl_down(s, off); ss += __shfl_down(ss, off); }
        int wave = tid >> 6, lane = tid & 63;
        if (lane == 0) { rs[wave] = s; rss[wave] = ss; }
        __syncthreads();
        if (tid == 0) {
            float S1 = rs[0] + rs[1] + rs[2] + rs[3];
            float S2 = rss[0] + rss[1] + rss[2] + rss[3];
            float mean = S1 * (1.f / 65536.f);
            float var = S2 * (1.f / 65536.f) - mean * mean;
            stats[bg * 2] = mean;
            stats[bg * 2 + 1] = rsqrtf(var + 1e-5f);
        }
        return;
    }
    if (b < 976) {  // zero lsums
        ((float4*)lsums)[(b - 960) * 256 + tid] = (float4){0.f, 0.f, 0.f, 0.f};
        return;
    }
    {   // bpv
        int o0 = (b - 976) * 64;
        int wave = tid >> 6, lane = tid & 63;
        const float4* bvv = (const float4*)(b_qkv + 1024);
        float4 v0 = bvv[lane * 2], v1 = bvv[lane * 2 + 1];
        for (int it = 0; it < 16; ++it) {
            int o = o0 + wave * 16 + it;
            const float4* wr = (const float4*)(w_proj + (size_t)o * CDIM);
            float4 a0 = wr[lane * 2], a1 = wr[lane * 2 + 1];
            float s = a0.x * v0.x + a0.y * v0.y + a0.z * v0.z + a0.w * v0.w
                    + a1.x * v1.x + a1.y * v1.y + a1.z * v1.z + a1.w * v1.w;
#pragma unroll
            for (int off = 32; off; off >>= 1) s += __shfl_down(s, off);
            if (lane == 0) bpv[o] = s;
        }
    }
}

// ================= shared 128x128x64 MFMA core (global_load_lds + XOR swizzle) =================
__device__ __forceinline__ void gemm_core(
    const u16* __restrict__ Ab, const u16* __restrict__ Bb, int K, int lda, int ldb,
    int m0, int n0, u16* As, u16* Bs, floatx4 (&acc)[4][4]) {
    int tid = threadIdx.x;
    int lane = tid & 63, wave = tid >> 6, quad = lane >> 4, lrow = lane & 15;
    int wm = (wave >> 1) << 6, wn = (wave & 1) << 6;
    for (int k0 = 0; k0 < K; k0 += 64) {
#pragma unroll
        for (int it = 0; it < 4; ++it) {
            int c = it * 256 + tid;
            int r = c >> 3, p = c & 7;
            int kc = p ^ (r & 7);               // slot p holds global chunk p^(r&7)
            load_lds16(Ab + (size_t)(m0 + r) * lda + k0 + (kc << 3), &As[c << 3]);
            load_lds16(Bb + (size_t)(n0 + r) * ldb + k0 + (kc << 3), &Bs[c << 3]);
        }
        __syncthreads();
#pragma unroll
        for (int s = 0; s < 2; ++s) {
            short8 af[4], bf[4];
#pragma unroll
            for (int i = 0; i < 4; ++i) {
                int R = wm + i * 16 + lrow;
                int p = (s * 4 + quad) ^ (R & 7);
                af[i] = *(const short8*)&As[(R << 6) + (p << 3)];
            }
#pragma unroll
            for (int j = 0; j < 4; ++j) {
                int R = wn + j * 16 + lrow;
                int p = (s * 4 + quad) ^ (R & 7);
                bf[j] = *(const short8*)&Bs[(R << 6) + (p << 3)];
            }
#pragma unroll
            for (int i = 0; i < 4; ++i)
#pragma unroll
                for (int j = 0; j < 4; ++j)
                    acc[i][j] = __builtin_amdgcn_mfma_f32_16x16x32_bf16(af[i], bf[j], acc[i][j], 0, 0, 0);
        }
        __syncthreads();
    }
}

#define ACC_INIT floatx4 acc[4][4]; \
    _Pragma("unroll") for (int i = 0; i < 4; ++i) \
    _Pragma("unroll") for (int j = 0; j < 4; ++j) acc[i][j] = (floatx4){0.f, 0.f, 0.f, 0.f};

#define EPILOG_IDX int lane = threadIdx.x & 63, wave = threadIdx.x >> 6; \
    int quad = lane >> 4, lrow = lane & 15; \
    int wm = (wave >> 1) << 6, wn = (wave & 1) << 6;

// ================= D2: GN apply+transpose (z<16) + Wpv GEMM (z==16) =================
#define TSTR 66
__global__ __launch_bounds__(256) void gn_wpv_kernel(
    const float* __restrict__ x, const float* __restrict__ gamma, const float* __restrict__ beta,
    const float* __restrict__ stats, u16* __restrict__ hT,
    const u16* __restrict__ wproj_bf, const u16* __restrict__ wv_t, u16* __restrict__ wmega) {
    __shared__ u16 smem[2 * 128 * 64];
    int tid = threadIdx.x;
    if (blockIdx.z == 16) {  // Wpv = wproj_bf . wv_t^T -> wmega rows 1024..1535
        if (blockIdx.x >= 4 || blockIdx.y >= 4) return;
        int m0 = blockIdx.y << 7, n0 = blockIdx.x << 7;
        ACC_INIT;
        gemm_core(wproj_bf, wv_t, CDIM, CDIM, CDIM, m0, n0, smem, smem + 128 * 64, acc);
        EPILOG_IDX;
#pragma unroll
        for (int i = 0; i < 4; ++i)
#pragma unroll
            for (int j = 0; j < 4; ++j)
#pragma unroll
                for (int r = 0; r < 4; ++r) {
                    int R = m0 + wm + i * 16 + (quad << 2) + r;
                    int Cc = n0 + wn + j * 16 + lrow;
                    wmega[(size_t)(1024 + R) * CDIM + Cc] = f2bf(acc[i][j][r]);
                }
        return;
    }
    u16* t = smem;
    int b = blockIdx.z, c0 = blockIdx.y << 6, n0 = blockIdx.x << 6;
    const float* xb = x + ((size_t)b * CDIM + c0) * NSPAT + n0;
#pragma unroll
    for (int p = 0; p < 4; ++p) {
        int cl = p * 16 + (tid >> 4);
        int nl = (tid & 15) << 2;
        int c = c0 + cl;
        int bg = b * NGROUP + (c >> 6);
        float ga = gamma[c] * stats[bg * 2 + 1];
        float be = beta[c] - stats[bg * 2] * ga;
        float4 v = *(const float4*)(xb + (size_t)cl * NSPAT + nl);
        u16* dst = &t[cl * TSTR + nl];
        dst[0] = f2bf(v.x * ga + be);
        dst[1] = f2bf(v.y * ga + be);
        dst[2] = f2bf(v.z * ga + be);
        dst[3] = f2bf(v.w * ga + be);
    }
    __syncthreads();
    u16* hb = hT + ((size_t)b * NSPAT + n0) * CDIM + c0;
#pragma unroll
    for (int p = 0; p < 4; ++p) {
        int nl = p * 16 + (tid >> 4);
        int cl4 = (tid & 15) << 2;
        ushort4 o;
        o.x = t[(cl4 + 0) * TSTR + nl];
        o.y = t[(cl4 + 1) * TSTR + nl];
        o.z = t[(cl4 + 2) * TSTR + nl];
        o.w = t[(cl4 + 3) * TSTR + nl];
        *(ushort4*)(hb + (size_t)nl * CDIM + cl4) = o;
    }
}

// ================= D3: qkv-mega: [q;k;WV] = wmega . h + [b_qkv(qk); bpv] =================
// grid (BATCH, 8, 12): batch in x for XCD affinity.
__global__ __launch_bounds__(256) void qkv_kernel(
    const u16* __restrict__ wmega, const u16* __restrict__ hT,
    const float* __restrict__ b_qkv, const float* __restrict__ bpv,
    u16* __restrict__ qkT, u16* __restrict__ WV) {
    __shared__ u16 As[128 * 64];
    __shared__ u16 Bs[128 * 64];
    int z = blockIdx.x;
    int n0 = blockIdx.y << 7;
    int m0 = blockIdx.z << 7;
    const u16* Bb = hT + (size_t)z * CDIM * NSPAT;
    ACC_INIT;
    gemm_core(wmega, Bb, CDIM, CDIM, CDIM, m0, n0, As, Bs, acc);
    EPILOG_IDX;
    if (blockIdx.z < 8) {  // q,k rows: transposed packed store to qkT[n][o], ldc=1024
        u16* qk = qkT + (size_t)z * NSPAT * NSPAT;
#pragma unroll
        for (int i = 0; i < 4; ++i)
#pragma unroll
            for (int j = 0; j < 4; ++j) {
                int R0 = m0 + wm + i * 16 + (quad << 2);
                int Cc = n0 + wn + j * 16 + lrow;
                uint2 u;
                u.x = f2bf2(acc[i][j][0] + b_qkv[R0 + 0], acc[i][j][1] + b_qkv[R0 + 1]);
                u.y = f2bf2(acc[i][j][2] + b_qkv[R0 + 2], acc[i][j][3] + b_qkv[R0 + 3]);
                *(uint2*)&qk[(size_t)Cc * NSPAT + R0] = u;
            }
    } else {  // WV rows: natural store WV[o][n] + bpv
        u16* Wp = WV + (size_t)z * CDIM * NSPAT;
#pragma unroll
        for (int i = 0; i < 4; ++i)
#pragma unroll
            for (int j = 0; j < 4; ++j)
#pragma unroll
                for (int r = 0; r < 4; ++r) {
                    int R = m0 - 1024 + wm + i * 16 + (quad << 2) + r;
                    int Cc = n0 + wn + j * 16 + lrow;
                    Wp[(size_t)R * NSPAT + Cc] = f2bf(acc[i][j][r] + bpv[R]);
                }
    }
}

// ================= D4: scores (swapped operands): D[j][i] = k_j . q_i =================
// A = kT rows (M=j), B = qT rows (N=i)  ->  C/D col=i (lane), row=j (reg).
// grid (BATCH, 8, 8): y = i-tile, z = j-tile.
__global__ __launch_bounds__(256) void scores_kernel(
    const u16* __restrict__ qkT, u16* __restrict__ P, float* __restrict__ lsums, float scale) {
    __shared__ u16 As[128 * 64];
    __shared__ u16 Bs[128 * 64];
    int z = blockIdx.x;
    int n0 = blockIdx.y << 7;                // i tile (N-dim)
    int m0 = blockIdx.z << 7;                // j tile (M-dim)
    const u16* qb = qkT + (size_t)z * NSPAT * NSPAT;
    ACC_INIT;
    gemm_core(qb + CDIM, qb, CDIM, NSPAT, NSPAT, m0, n0, As, Bs, acc);
    EPILOG_IDX;
    u16* Pp = P + (size_t)z * NSPAT * NSPAT;
    float* ls = lsums + (size_t)z * NSPAT;
#pragma unroll
    for (int nj = 0; nj < 4; ++nj) {
        int Ci = n0 + wn + nj * 16 + lrow;       // i (column of D)
        float part = 0.f;
#pragma unroll
        for (int mi = 0; mi < 4; ++mi) {
            int Rj0 = m0 + wm + mi * 16 + (quad << 2);   // j (rows of D), 4 consecutive
            float e0 = __expf(acc[mi][nj][0] * scale);
            float e1 = __expf(acc[mi][nj][1] * scale);
            float e2 = __expf(acc[mi][nj][2] * scale);
            float e3 = __expf(acc[mi][nj][3] * scale);
            part += (e0 + e1) + (e2 + e3);
            uint2 u;
            u.x = f2bf2(e0, e1);
            u.y = f2bf2(e2, e3);
            *(uint2*)&Pp[(size_t)Ci * NSPAT + Rj0] = u;
        }
        part += __shfl_xor(part, 16);
        part += __shfl_xor(part, 32);
        if (lane < 16) atomicAdd(&ls[Ci], part);
    }
}

// ================= D5: final (swapped operands): D[i][o] = P_i . WV_o =================
// A = P rows (M=i), B = WV rows (N=o)  ->  col=o (lane), row=i (reg, 4 consecutive).
// grid (BATCH, 4, 8): y = o-tile, z = i-tile.
__global__ __launch_bounds__(256) void final_kernel(
    const u16* __restrict__ WV, const u16* __restrict__ P, const float* __restrict__ lsums,
    const float* __restrict__ bias, const float* __restrict__ x, float* __restrict__ out) {
    __shared__ u16 As[128 * 64];
    __shared__ u16 Bs[128 * 64];
    int z = blockIdx.x;
    int n0 = blockIdx.y << 7;                // o tile (N-dim, 4 tiles)
    int m0 = blockIdx.z << 7;                // i tile (M-dim, 8 tiles)
    const u16* Pb = P + (size_t)z * NSPAT * NSPAT;
    const u16* WVb = WV + (size_t)z * CDIM * NSPAT;
    ACC_INIT;
    gemm_core(Pb, WVb, NSPAT, NSPAT, NSPAT, m0, n0, As, Bs, acc);
    EPILOG_IDX;
    float* Op = out + (size_t)z * CDIM * NSPAT;
    const float* xr = x + (size_t)z * CDIM * NSPAT;
    const float* li = lsums + (size_t)z * NSPAT;
#pragma unroll
    for (int mi = 0; mi < 4; ++mi) {
        int Ri0 = m0 + wm + mi * 16 + (quad << 2);       // i, 4 consecutive
        float4 lv = *(const float4*)&li[Ri0];
        float s0 = __builtin_amdgcn_rcpf(lv.x);
        float s1 = __builtin_amdgcn_rcpf(lv.y);
        float s2 = __builtin_amdgcn_rcpf(lv.z);
        float s3 = __builtin_amdgcn_rcpf(lv.w);
#pragma unroll
        for (int nj = 0; nj < 4; ++nj) {
            int Co = n0 + wn + nj * 16 + lrow;           // o
            float bv = bias[Co];
            size_t off = (size_t)Co * NSPAT + Ri0;
            float4 xv = *(const float4*)&xr[off];
            float4 o;
            o.x = acc[mi][nj][0] * s0 + bv + xv.x;
            o.y = acc[mi][nj][1] * s1 + bv + xv.y;
            o.z = acc[mi][nj][2] * s2 + bv + xv.z;
            o.w = acc[mi][nj][3] * s3 + bv + xv.w;
            *(float4*)&Op[off] = o;
        }
    }
}

// ================= launch =================
extern "C" void kernel_launch(void* const* d_in, const int* in_sizes, int n_in,
                              void* d_out, int out_size, void* d_ws, size_t ws_size,
                              hipStream_t stream) {
    const float* x      = (const float*)d_in[0];
    const float* gamma  = (const float*)d_in[1];
    const float* beta   = (const float*)d_in[2];
    const float* w_qkv  = (const float*)d_in[3];
    const float* b_qkv  = (const float*)d_in[4];
    const float* w_proj = (const float*)d_in[5];
    const float* b_proj = (const float*)d_in[6];
    float* out = (float*)d_out;

    const size_t CN = (size_t)CDIM * NSPAT;   // 524288
    const size_t NN = (size_t)NSPAT * NSPAT;  // 1048576
    const float SCALE = 0.044194173824159216f;

    char* ws = (char*)d_ws;
    float* stats   = (float*)ws;                              // 1 KB
    float* bpv     = (float*)(ws + 1024);                     // 2 KB
    u16* wmega     = (u16*)(ws + 4096);                       // [Wq;Wk;Wpv] 1536x512 bf16
    u16* wproj_bf  = wmega + (size_t)3 * CDIM * CDIM;         // 0.5 MB
    u16* wv_t      = wproj_bf + (size_t)CDIM * CDIM;          // 0.5 MB
    u16* hT        = wv_t + (size_t)CDIM * CDIM;              // 16.8 MB [n][c]
    u16* qkT       = hT + BATCH * CN;                         // 33.5 MB [n][q,k:1024]
    u16* WV        = qkT + BATCH * NN;                        // 16.8 MB [o][n]
    u16* P         = WV + BATCH * CN;                         // 33.5 MB [i][j] unnorm
    float* lsums   = (float*)(P + BATCH * NN);                // 64 KB

    prep_kernel<<<984, 256, 0, stream>>>(
        w_qkv, w_proj, b_qkv, x, wmega, wproj_bf, wv_t, stats, lsums, bpv);

    gn_wpv_kernel<<<dim3(16, 8, 17), 256, 0, stream>>>(
        x, gamma, beta, stats, hT, wproj_bf, wv_t, wmega);

    qkv_kernel<<<dim3(BATCH, 8, 12), 256, 0, stream>>>(
        wmega, hT, b_qkv, bpv, qkT, WV);

    scores_kernel<<<dim3(BATCH, 8, 8), 256, 0, stream>>>(qkT, P, lsums, SCALE);

    final_kernel<<<dim3(BATCH, 4, 8), 256, 0, stream>>>(WV, P, lsums, b_proj, x, out);
}